// Round 1
// baseline (363.898 us; speedup 1.0000x reference)
//
#include <hip/hip_runtime.h>
#include <hip/hip_cooperative_groups.h>

namespace cg = cooperative_groups;

// N=1024, Cin=1024, Cy=256, H=W=128, inter=256 -- all fp32
#define HWDIM 128
#define NPIX  (HWDIM * HWDIM)   // 16384
#define CY    256
#define INTER 256
#define KTAPS 9
#define WEN   (CY * KTAPS)      // 2304
#define NW1   32                // k1 c-split (we partials)
#define NCS   8                 // A channel groups
#define CPG   32                // channels per A group
#define NPART2 256              // softmax partial pairs
#define NRG   4                 // q row-group split

// ---------------------------------------------------------------------------
// Algebra: softmax over axis 1 cancels s_theta (constant along that axis) and
// the uniform phi-bias shift -> x, theta_*, phi_b dead. All 1024 output rows
// identical: z = gamma*(g_b + g_w . q).
//   we[cy,t] = sum_c wp[c]*phi_w[c,cy,t]
//   A[cg,t,pix] = sum_{cy in cg} we[cy,t]*y[cy,pix]     (tap-first: NO halo)
//   sphi[h,w] = sum_{cg,t} A[cg,t, shifted(h,w)]        (tiny L2 gather)
//   p = softmax(sphi);  q[cy,t] = sum_hw p[h-kh+1,w-kw+1]*y[cy,h,w]
//
// R(this session): the six tiny dispatches cost ~45us of launch gaps/ramps on
// ~14us of bodies. Fuse into ONE cooperative kernel, 5 grid.sync()s. Phase
// bodies copied verbatim (bit-identical numerics). k4-phase: 2 cy per block
// sharing one p-tile staging. Fallback to 6-kernel path if coop launch fails.
// NOTE (profiling): harness re-poison of the 256MB d_ws (fillBufferAligned,
// ~44us @ 6TB/s) + input restores are INSIDE dur_us -> ~58us fixed floor.
// ---------------------------------------------------------------------------

__device__ __forceinline__ float wave_red_sum(float v) {
    #pragma unroll
    for (int s = 32; s > 0; s >>= 1) v += __shfl_down(v, s, 64);
    return v;
}
__device__ __forceinline__ float wave_red_max(float v) {
    #pragma unroll
    for (int s = 32; s > 0; s >>= 1) v = fmaxf(v, __shfl_down(v, s, 64));
    return v;
}

// ===========================================================================
// Fused single-dispatch pipeline. grid=512x256, 2 blocks/CU co-resident.
// ===========================================================================
__global__ __launch_bounds__(256, 2)
void fused_all(const float* __restrict__ y,
               const float* __restrict__ phi_w,
               const float* __restrict__ concat_w,
               const float* __restrict__ g_w,
               const float* __restrict__ g_b,
               const float* __restrict__ gamma,
               float* __restrict__ out, int out_size,
               float* __restrict__ we_part,
               float* __restrict__ A,
               float* __restrict__ sphi,
               float* __restrict__ partials,
               float* __restrict__ q_part,
               float* __restrict__ row_part)
{
    cg::grid_group grid = cg::this_grid();
    __shared__ float smem[4500];          // 18 KB: p-tile (4420) + reductions
    const int b = blockIdx.x;
    const int t = threadIdx.x;
    const int wid = t >> 6, lane = t & 63;

    // ---- P1: we_part[cg][o] = sum_{c in 8-slice} wp[c]*phi_w[c,o]
    // 288 active blocks = 32 cg x 9 og; coalesced phi_w rows.
    if (b < 288) {
        int cgi = b / 9, og = b - cgi * 9;
        int o = og * 256 + t;
        const float* pw = phi_w + o;
        float acc = 0.f;
        #pragma unroll
        for (int j = 0; j < 8; ++j) {
            int c = cgi * 8 + j;
            acc = fmaf(concat_w[INTER + c], pw[c * WEN], acc);
        }
        we_part[cgi * WEN + o] = acc;
    }
    grid.sync();

    // ---- P2: A[cg][k][pix] = sum_{ch in cg} we[cg*CPG+ch,k]*y[ch,pix]
    // all 512 blocks = 8 cg x 64 pg; streams y coalesced once.
    {
        float* swe = smem;                // 288
        const int pg = b & 63, cgi = b >> 6;

        for (int i = t; i < CPG * KTAPS; i += 256) {
            float s = 0.f;
            #pragma unroll
            for (int p = 0; p < NW1; ++p)
                s += we_part[p * WEN + cgi * CPG * KTAPS + i];
            swe[i] = s;
        }
        __syncthreads();

        int pix = pg * 256 + t;
        float acc[KTAPS];
        #pragma unroll
        for (int k = 0; k < KTAPS; ++k) acc[k] = 0.f;

        const float* yp = y + (size_t)cgi * CPG * NPIX + pix;
        #pragma unroll 8
        for (int ch = 0; ch < CPG; ++ch) {
            float yv = yp[ch * NPIX];
            const float* wk = swe + ch * KTAPS;   // wave-uniform LDS broadcast
            #pragma unroll
            for (int k = 0; k < KTAPS; ++k)
                acc[k] = fmaf(wk[k], yv, acc[k]);
        }
        #pragma unroll
        for (int k = 0; k < KTAPS; ++k)
            A[(size_t)(cgi * KTAPS + k) * NPIX + pix] = acc[k];
    }
    grid.sync();

    // ---- P3: sphi[pix] = sum_{cg,k} A[cg][k][shifted]; softmax partials.
    // 256 active blocks; block covers 64 pixels x 4 term-groups.
    if (b < NPART2) {
        float* sred = smem;               // 256
        int tg = t >> 6, pl = t & 63;
        int pix = b * 64 + pl;
        int h = pix >> 7, w = pix & 127;

        int idx[KTAPS]; bool val[KTAPS];
        #pragma unroll
        for (int kh = 0; kh < 3; ++kh)
            #pragma unroll
            for (int kw = 0; kw < 3; ++kw) {
                int hh = h + kh - 1, ww = w + kw - 1;
                int k = kh * 3 + kw;
                val[k] = ((unsigned)hh < HWDIM) & ((unsigned)ww < HWDIM);
                idx[k] = hh * HWDIM + ww;
            }

        float acc = 0.f;
        #pragma unroll
        for (int cc = 0; cc < 2; ++cc) {
            const float* Ab = A + (size_t)(tg * 2 + cc) * KTAPS * NPIX;
            #pragma unroll
            for (int k = 0; k < KTAPS; ++k)
                if (val[k]) acc += Ab[(size_t)k * NPIX + idx[k]];
        }
        sred[t] = acc;
        __syncthreads();

        if (t < 64) {
            float v = sred[t] + sred[t + 64] + sred[t + 128] + sred[t + 192];
            sphi[b * 64 + t] = v;
            float m = wave_red_max(v);
            float M = __shfl(m, 0, 64);
            float e = expf(v - M);
            float s = wave_red_sum(e);
            if (t == 0) {
                partials[2 * b]     = M;
                partials[2 * b + 1] = s;
            }
        }
    }
    grid.sync();

    // ---- P4: q_part[rg][cy*9+k] over a 32-row slice. 512 blocks =
    // 4 rg x 128 bc; each block handles cy0=2*bc, cy1=2*bc+1 sharing one
    // staged p tile (halves the redundant expf stagings vs 1024 blocks).
    {
        float* sp  = smem;                        // 34*130 = 4420
        float* s4m = smem + 4420;                 // 4
        float* s4s = smem + 4424;                 // 4
        float (*sq4)[18] = (float (*)[18])(smem + 4428);  // 4x18
        const int rg = b >> 7;
        const int bc = b & 127;
        const int cy0 = bc * 2, cy1 = cy0 + 1;

        // merge 256 partial pairs -> M, invS (thread t owns pair t)
        float m = partials[2 * t], s = partials[2 * t + 1];
        float wm = wave_red_max(m);
        if (lane == 0) s4m[wid] = wm;
        __syncthreads();
        float M = fmaxf(fmaxf(s4m[0], s4m[1]), fmaxf(s4m[2], s4m[3]));
        float sv = s * expf(m - M);
        float wsum = wave_red_sum(sv);
        if (lane == 0) s4s[wid] = wsum;
        __syncthreads();
        float invS = 1.f / (s4s[0] + s4s[1] + s4s[2] + s4s[3]);

        // stage p tile: sp[r][col] = p[rg*32 + r - 1][col - 1], zero-padded
        for (int i = t; i < 34 * 130; i += 256) {
            int r = i / 130, col = i - r * 130;
            int gr = rg * 32 + r - 1, gc = col - 1;
            float v = 0.f;
            if ((unsigned)gr < HWDIM && (unsigned)gc < HWDIM)
                v = expf(sphi[gr * HWDIM + gc] - M) * invS;
            sp[i] = v;
        }
        __syncthreads();

        const float* yc0 = y + (size_t)cy0 * NPIX;
        const float* yc1 = y + (size_t)cy1 * NPIX;
        float acc0[KTAPS], acc1[KTAPS];
        #pragma unroll
        for (int k = 0; k < KTAPS; ++k) { acc0[k] = 0.f; acc1[k] = 0.f; }
        int c = t & 127, vg = t >> 7;

        for (int j = 0; j < 4; ++j) {
            int lr0 = vg * 4 + j * 8;             // local row base (0..28)
            float pv[6][3];
            #pragma unroll
            for (int u = 0; u < 6; ++u)
                #pragma unroll
                for (int v = 0; v < 3; ++v)
                    pv[u][v] = sp[(lr0 + u) * 130 + c + v];
            #pragma unroll
            for (int dr = 0; dr < 4; ++dr) {
                float y0 = yc0[(rg * 32 + lr0 + dr) * HWDIM + c];
                float y1 = yc1[(rg * 32 + lr0 + dr) * HWDIM + c];
                #pragma unroll
                for (int kh = 0; kh < 3; ++kh)
                    #pragma unroll
                    for (int kw = 0; kw < 3; ++kw) {
                        float p = pv[dr + 2 - kh][2 - kw];
                        acc0[kh * 3 + kw] = fmaf(p, y0, acc0[kh * 3 + kw]);
                        acc1[kh * 3 + kw] = fmaf(p, y1, acc1[kh * 3 + kw]);
                    }
            }
        }

        #pragma unroll
        for (int k = 0; k < KTAPS; ++k) {
            float v0 = wave_red_sum(acc0[k]);
            float v1 = wave_red_sum(acc1[k]);
            if (lane == 0) { sq4[wid][k] = v0; sq4[wid][9 + k] = v1; }
        }
        __syncthreads();
        if (t < KTAPS) {
            q_part[rg * WEN + cy0 * KTAPS + t] =
                sq4[0][t] + sq4[1][t] + sq4[2][t] + sq4[3][t];
            q_part[rg * WEN + cy1 * KTAPS + t] =
                sq4[0][9 + t] + sq4[1][9 + t] + sq4[2][9 + t] + sq4[3][9 + t];
        }
    }
    grid.sync();

    // ---- P5: row_part[half][c] = g_w[c, half-slice] . q  (merge 4 partials)
    // all 512 blocks = 2 half x 256 c
    {
        float* s4 = smem;                 // 4
        int c = b & 255, half = b >> 8;
        int base = half * (WEN / 2);      // 1152

        const float* gw = g_w + (size_t)c * WEN;
        float acc = 0.f;
        #pragma unroll
        for (int j = 0; j < 5; ++j) {
            int o = base + j * 256 + t;
            if (o < base + WEN / 2) {
                float qv = q_part[o] + q_part[WEN + o] +
                           q_part[2 * WEN + o] + q_part[3 * WEN + o];
                acc = fmaf(gw[o], qv, acc);
            }
        }
        float v = wave_red_sum(acc);
        if (lane == 0) s4[wid] = v;
        __syncthreads();
        if (t == 0)
            row_part[half * 256 + c] = s4[0] + s4[1] + s4[2] + s4[3];
    }
    grid.sync();

    // ---- P6: out[i*256+c] = gamma*(g_b[c] + row0[c] + row1[c]); col c == t
    {
        float val = gamma[0] * (g_b[t] + row_part[t] + row_part[256 + t]);
        int gid0 = b * 256 + t;
        if (gid0 < out_size) out[gid0] = val;
        int gid1 = (b + 512) * 256 + t;
        if (gid1 < out_size) out[gid1] = val;
    }
}

// ===========================================================================
// Fallback: the proven 6-kernel pipeline (unchanged), used only if the
// cooperative launch is rejected at runtime.
// ===========================================================================
__global__ void k1_wepart(const float* __restrict__ phi_w,
                          const float* __restrict__ concat_w,
                          float* __restrict__ we_part) {
    int b = blockIdx.x, t = threadIdx.x;
    int cg = b / 9, og = b - cg * 9;
    int o = og * 256 + t;
    const float* pw = phi_w + o;
    float acc = 0.f;
    #pragma unroll
    for (int j = 0; j < 8; ++j) {
        int c = cg * 8 + j;
        acc = fmaf(concat_w[INTER + c], pw[c * WEN], acc);
    }
    we_part[cg * WEN + o] = acc;
}

__global__ void k2a_taps(const float* __restrict__ y,
                         const float* __restrict__ we_part,
                         float* __restrict__ A) {
    __shared__ float swe[CPG * KTAPS];
    int t = threadIdx.x;
    int pg = blockIdx.x & 63;
    int cg = blockIdx.x >> 6;

    for (int i = t; i < CPG * KTAPS; i += 256) {
        float s = 0.f;
        #pragma unroll
        for (int p = 0; p < NW1; ++p)
            s += we_part[p * WEN + cg * CPG * KTAPS + i];
        swe[i] = s;
    }
    __syncthreads();

    int pix = pg * 256 + t;
    float acc[KTAPS];
    #pragma unroll
    for (int k = 0; k < KTAPS; ++k) acc[k] = 0.f;

    const float* yp = y + (size_t)cg * CPG * NPIX + pix;
    #pragma unroll 4
    for (int ch = 0; ch < CPG; ++ch) {
        float yv = yp[ch * NPIX];
        const float* wk = swe + ch * KTAPS;
        #pragma unroll
        for (int k = 0; k < KTAPS; ++k)
            acc[k] = fmaf(wk[k], yv, acc[k]);
    }
    #pragma unroll
    for (int k = 0; k < KTAPS; ++k)
        A[(size_t)(cg * KTAPS + k) * NPIX + pix] = acc[k];
}

__global__ void k2b_sphi(const float* __restrict__ A,
                         float* __restrict__ sphi,
                         float* __restrict__ partials) {
    __shared__ float sred[256];
    int t = threadIdx.x;
    int tg = t >> 6, pl = t & 63;
    int pix = blockIdx.x * 64 + pl;
    int h = pix >> 7, w = pix & 127;

    int idx[KTAPS]; bool val[KTAPS];
    #pragma unroll
    for (int kh = 0; kh < 3; ++kh)
        #pragma unroll
        for (int kw = 0; kw < 3; ++kw) {
            int hh = h + kh - 1, ww = w + kw - 1;
            int k = kh * 3 + kw;
            val[k] = ((unsigned)hh < HWDIM) & ((unsigned)ww < HWDIM);
            idx[k] = hh * HWDIM + ww;
        }

    float acc = 0.f;
    #pragma unroll
    for (int cc = 0; cc < 2; ++cc) {
        const float* Ab = A + (size_t)(tg * 2 + cc) * KTAPS * NPIX;
        #pragma unroll
        for (int k = 0; k < KTAPS; ++k)
            if (val[k]) acc += Ab[(size_t)k * NPIX + idx[k]];
    }
    sred[t] = acc;
    __syncthreads();

    if (t < 64) {
        float v = sred[t] + sred[t + 64] + sred[t + 128] + sred[t + 192];
        sphi[blockIdx.x * 64 + t] = v;
        float m = wave_red_max(v);
        float M = __shfl(m, 0, 64);
        float e = expf(v - M);
        float s = wave_red_sum(e);
        if (t == 0) {
            partials[2 * blockIdx.x]     = M;
            partials[2 * blockIdx.x + 1] = s;
        }
    }
}

__global__ void k4_q(const float* __restrict__ y,
                     const float* __restrict__ sphi,
                     const float* __restrict__ partials,
                     float* __restrict__ q_part) {
    __shared__ float sp[34 * 130];
    __shared__ float s4m[4], s4s[4];
    __shared__ float sq4[4][KTAPS];
    int cy = blockIdx.x & 255;
    int rg = blockIdx.x >> 8;
    int t = threadIdx.x;
    int wid = t >> 6, lane = t & 63;

    float m = partials[2 * t], s = partials[2 * t + 1];
    float wm = wave_red_max(m);
    if (lane == 0) s4m[wid] = wm;
    __syncthreads();
    float M = fmaxf(fmaxf(s4m[0], s4m[1]), fmaxf(s4m[2], s4m[3]));
    float sv = s * expf(m - M);
    float wsum = wave_red_sum(sv);
    if (lane == 0) s4s[wid] = wsum;
    __syncthreads();
    float invS = 1.f / (s4s[0] + s4s[1] + s4s[2] + s4s[3]);

    for (int i = t; i < 34 * 130; i += 256) {
        int r = i / 130, col = i - r * 130;
        int gr = rg * 32 + r - 1, gc = col - 1;
        float v = 0.f;
        if ((unsigned)gr < HWDIM && (unsigned)gc < HWDIM)
            v = expf(sphi[gr * HWDIM + gc] - M) * invS;
        sp[i] = v;
    }
    __syncthreads();

    const float* yc = y + (size_t)cy * NPIX;
    float acc[KTAPS];
    #pragma unroll
    for (int k = 0; k < KTAPS; ++k) acc[k] = 0.f;
    int c = t & 127, vg = t >> 7;

    for (int j = 0; j < 4; ++j) {
        int lr0 = vg * 4 + j * 8;
        float pv[6][3];
        #pragma unroll
        for (int u = 0; u < 6; ++u)
            #pragma unroll
            for (int v = 0; v < 3; ++v)
                pv[u][v] = sp[(lr0 + u) * 130 + c + v];
        #pragma unroll
        for (int dr = 0; dr < 4; ++dr) {
            float yv = yc[(rg * 32 + lr0 + dr) * HWDIM + c];
            #pragma unroll
            for (int kh = 0; kh < 3; ++kh)
                #pragma unroll
                for (int kw = 0; kw < 3; ++kw)
                    acc[kh * 3 + kw] = fmaf(pv[dr + 2 - kh][2 - kw], yv,
                                            acc[kh * 3 + kw]);
        }
    }

    #pragma unroll
    for (int k = 0; k < KTAPS; ++k) {
        float v = wave_red_sum(acc[k]);
        if (lane == 0) sq4[wid][k] = v;
    }
    __syncthreads();
    if (t < KTAPS)
        q_part[rg * WEN + cy * KTAPS + t] =
            sq4[0][t] + sq4[1][t] + sq4[2][t] + sq4[3][t];
}

__global__ void k5_row(const float* __restrict__ g_w,
                       const float* __restrict__ q_part,
                       float* __restrict__ row_part) {
    __shared__ float s4[4];
    int t = threadIdx.x;
    int c = blockIdx.x & 255, half = blockIdx.x >> 8;
    int base = half * (WEN / 2);

    const float* gw = g_w + (size_t)c * WEN;
    float acc = 0.f;
    #pragma unroll
    for (int j = 0; j < 5; ++j) {
        int o = base + j * 256 + t;
        if (o < base + WEN / 2) {
            float qv = q_part[o] + q_part[WEN + o] +
                       q_part[2 * WEN + o] + q_part[3 * WEN + o];
            acc = fmaf(gw[o], qv, acc);
        }
    }
    float v = wave_red_sum(acc);
    int wid = t >> 6, lane = t & 63;
    if (lane == 0) s4[wid] = v;
    __syncthreads();
    if (t == 0)
        row_part[half * 256 + c] = s4[0] + s4[1] + s4[2] + s4[3];
}

__global__ void k6_bcast(const float* __restrict__ row_part,
                         const float* __restrict__ g_b,
                         const float* __restrict__ gamma,
                         float* __restrict__ out, int out_size) {
    __shared__ float sr[256];
    int t = threadIdx.x;
    sr[t] = gamma[0] * (g_b[t] + row_part[t] + row_part[256 + t]);
    __syncthreads();
    int gid = blockIdx.x * 256 + t;
    if (gid < out_size) out[gid] = sr[t];
}

extern "C" void kernel_launch(void* const* d_in, const int* in_sizes, int n_in,
                              void* d_out, int out_size, void* d_ws, size_t ws_size,
                              hipStream_t stream) {
    // inputs: x, y, g_w, g_b, phi_w, phi_b, theta_w, theta_b, concat_w, gamma
    const float* y        = (const float*)d_in[1];
    const float* g_w      = (const float*)d_in[2];
    const float* g_b      = (const float*)d_in[3];
    const float* phi_w    = (const float*)d_in[4];
    const float* concat_w = (const float*)d_in[8];
    const float* gamma    = (const float*)d_in[9];
    float* out = (float*)d_out;

    float* ws       = (float*)d_ws;
    float* we_part  = ws;                            // 32*2304   = 73728
    float* A        = we_part + NW1 * WEN;           // 8*9*16384 = 1179648
    float* sphi     = A + (size_t)NCS * KTAPS * NPIX;// 16384
    float* partials = sphi + NPIX;                   // 512
    float* q_part   = partials + 2 * NPART2;         // 4*2304
    float* row_part = q_part + NRG * WEN;            // 512
    (void)in_sizes; (void)n_in; (void)ws_size;

    int osz = out_size;
    void* args[] = {
        (void*)&y, (void*)&phi_w, (void*)&concat_w, (void*)&g_w,
        (void*)&g_b, (void*)&gamma, (void*)&out, (void*)&osz,
        (void*)&we_part, (void*)&A, (void*)&sphi, (void*)&partials,
        (void*)&q_part, (void*)&row_part
    };
    hipError_t err = hipLaunchCooperativeKernel(
        reinterpret_cast<void*>(fused_all), dim3(512), dim3(256),
        args, 0, stream);

    if (err != hipSuccess) {
        // fallback: proven 6-kernel pipeline
        hipLaunchKernelGGL(k1_wepart, dim3(288),      dim3(256), 0, stream,
                           phi_w, concat_w, we_part);
        hipLaunchKernelGGL(k2a_taps,  dim3(64 * NCS), dim3(256), 0, stream,
                           y, we_part, A);
        hipLaunchKernelGGL(k2b_sphi,  dim3(NPART2),   dim3(256), 0, stream,
                           A, sphi, partials);
        hipLaunchKernelGGL(k4_q,      dim3(NRG * CY), dim3(256), 0, stream,
                           y, sphi, partials, q_part);
        hipLaunchKernelGGL(k5_row,    dim3(512),      dim3(256), 0, stream,
                           g_w, q_part, row_part);
        hipLaunchKernelGGL(k6_bcast,  dim3((out_size + 255) / 256), dim3(256),
                           0, stream, row_part, g_b, gamma, out, out_size);
    }
}